// Round 1
// baseline (43.897 us; speedup 1.0000x reference)
//
#include <hip/hip_runtime.h>
#include <hip/hip_bf16.h>

// Reference collapses to mean over the last axis (K=64):
//   e_x is constant along K, so up/down = (e_x * mean(x)) / e_x = mean(x).
// Pure memory-bound reduction: 256 MiB read, 4 MiB write.

__global__ __launch_bounds__(256) void K_ANP_41188736369107_kernel(
    const float* __restrict__ in, float* __restrict__ out, long long nrows) {
    // 16 lanes cooperate on one 64-element row (each lane loads one float4).
    const long long tid = (long long)blockIdx.x * blockDim.x + threadIdx.x;
    const int lane_in_row = (int)(tid & 15);
    const long long total_threads = (long long)gridDim.x * blockDim.x;
    const long long rows_per_iter = total_threads >> 4;

    for (long long row = tid >> 4; row < nrows; row += rows_per_iter) {
        const float4* p = reinterpret_cast<const float4*>(in + (row << 6));
        float4 v = p[lane_in_row];
        float s = (v.x + v.y) + (v.z + v.w);
        // butterfly reduce across the 16-lane group (stays within the group)
        s += __shfl_xor(s, 1);
        s += __shfl_xor(s, 2);
        s += __shfl_xor(s, 4);
        s += __shfl_xor(s, 8);
        if (lane_in_row == 0) out[row] = s * (1.0f / 64.0f);
    }
}

extern "C" void kernel_launch(void* const* d_in, const int* in_sizes, int n_in,
                              void* d_out, int out_size, void* d_ws, size_t ws_size,
                              hipStream_t stream) {
    const float* in = (const float*)d_in[0];
    float* out = (float*)d_out;
    const long long nrows = (long long)out_size;  // 8*256*512 = 1,048,576

    const int block = 256;
    // memory-bound: cap grid at ~8 blocks/CU * 256 CUs, grid-stride the rest
    long long rows_per_block_iter = block / 16;  // 16
    long long blocks_needed = (nrows + rows_per_block_iter - 1) / rows_per_block_iter;
    int grid = (int)((blocks_needed < 2048) ? blocks_needed : 2048);

    K_ANP_41188736369107_kernel<<<grid, block, 0, stream>>>(in, out, nrows);
}